// Round 1
// baseline (150.803 us; speedup 1.0000x reference)
//
#include <hip/hip_runtime.h>
#include <math.h>

#define N_NODES 50000
#define N_EDGES 800000
#define C2MAX 512      // cap on in-degree of node N-1
#define K1MAX 512      // cap on |S1 ∪ {N-1}|  (layer-1 destination nodes)
#define E1MAX 8192     // cap on total layer-1 edges
#define N2MAX 2048     // cap on nodes needing xw1
#define DEGMAX 1024    // per-node in-degree cap (layer 1)

// ---- pass 1: find edges into node N-1, mark their sources (and N-1) ----
__global__ void k_find2(const int* __restrict__ esrc, const int* __restrict__ edst,
                        int* cnt, int* slot1, int* e2src) {
    int i = blockIdx.x * blockDim.x + threadIdx.x;
    if (i == 0) slot1[N_NODES - 1] = -2;
    if (i >= N_EDGES) return;
    if (edst[i] == N_NODES - 1) {
        int s = esrc[i];
        int j = atomicAdd(&cnt[0], 1);
        if (j < C2MAX) e2src[j] = s;
        slot1[s] = -2;   // benign race: all writers store -2
    }
}

// ---- compact marked nodes -> slot ids ----
__global__ void k_compact1(int* cnt, int* slot1, int* nodes1) {
    int u = blockIdx.x * blockDim.x + threadIdx.x;
    if (u >= N_NODES) return;
    if (slot1[u] == -2) {
        int k = atomicAdd(&cnt[1], 1);
        if (k < K1MAX) { slot1[u] = k; nodes1[k] = u; }
        else slot1[u] = -1;
    }
}

// ---- pass 2: find edges into any layer-1 destination; mark xw1-needed nodes ----
__global__ void k_find1(const int* __restrict__ esrc, const int* __restrict__ edst,
                        int* cnt, const int* __restrict__ slot1,
                        const int* __restrict__ nodes1,
                        int* l1k, int* l1src, int* slot2) {
    int i = blockIdx.x * blockDim.x + threadIdx.x;
    int K1 = min(cnt[1], K1MAX);
    if (i < K1) slot2[nodes1[i]] = -2;   // dst nodes also need xw1 (for a_dst1)
    if (i >= N_EDGES) return;
    int d = edst[i];
    int k = slot1[d];
    if (k >= 0) {
        int s = esrc[i];
        int j = atomicAdd(&cnt[2], 1);
        if (j < E1MAX) { l1k[j] = k; l1src[j] = s; slot2[s] = -2; }
    }
}

__global__ void k_compact2(int* cnt, int* slot2, int* nodes2) {
    int u = blockIdx.x * blockDim.x + threadIdx.x;
    if (u >= N_NODES) return;
    if (slot2[u] == -2) {
        int m = atomicAdd(&cnt[3], 1);
        if (m < N2MAX) { slot2[u] = m; nodes2[m] = u; }
        else slot2[u] = -1;
    }
}

// ---- xw1 = x[u] @ W1^T for each needed node; also a_src1/a_dst1 ----
__global__ void k_xw1(const float* __restrict__ x, const float* __restrict__ W,
                      const float* __restrict__ attS, const float* __restrict__ attD,
                      const int* cnt, const int* __restrict__ nodes2,
                      float* xw1, float* as1, float* ad1) {
    int b = blockIdx.x;
    int n2 = min(cnt[3], N2MAX);
    if (b >= n2) return;
    int t = threadIdx.x;            // 0..255 -> output channel o = h*32+i
    int u = nodes2[b];
    __shared__ float xs[256];
    __shared__ float redS[256], redD[256];
    xs[t] = x[(size_t)u * 256 + t];
    __syncthreads();
    const float* wrow = W + (size_t)t * 256;
    float acc = 0.f;
#pragma unroll 8
    for (int c = 0; c < 256; ++c) acc = fmaf(xs[c], wrow[c], acc);
    xw1[(size_t)b * 256 + t] = acc;
    redS[t] = acc * attS[t];
    redD[t] = acc * attD[t];
    __syncthreads();
    if ((t & 31) == 0) {
        int h = t >> 5;
        float s = 0.f, d = 0.f;
        for (int i = 0; i < 32; ++i) { s += redS[t + i]; d += redD[t + i]; }
        as1[b * 8 + h] = s;
        ad1[b * 8 + h] = d;
    }
}

// ---- layer-1 attention softmax + aggregate + bias + exact GELU ----
__global__ void k_attn1(const int* cnt, const int* __restrict__ nodes1,
                        const int* __restrict__ slot2,
                        const int* __restrict__ l1k, const int* __restrict__ l1src,
                        const float* __restrict__ xw1, const float* __restrict__ as1,
                        const float* __restrict__ ad1,
                        const float* __restrict__ b1, float* h1g) {
    int k = blockIdx.x;
    int K1 = min(cnt[1], K1MAX);
    if (k >= K1) return;
    int t = threadIdx.x;
    int h = t >> 5;
    int c1 = min(cnt[2], E1MAX);
    __shared__ int elist[DEGMAX];
    __shared__ int ecnt;
    if (t == 0) ecnt = 0;
    __syncthreads();
    for (int j = t; j < c1; j += 256) {
        if (l1k[j] == k) {
            int p = atomicAdd(&ecnt, 1);
            if (p < DEGMAX) elist[p] = l1src[j];
        }
    }
    __syncthreads();
    int ne = min(ecnt, DEGMAX);
    int u = nodes1[k];
    float adst = ad1[slot2[u] * 8 + h];
    float m = -INFINITY;
    for (int j = 0; j < ne; ++j) {
        int s2 = slot2[elist[j]];
        float e = as1[s2 * 8 + h] + adst;
        e = (e >= 0.f) ? e : 0.2f * e;
        m = fmaxf(m, e);
    }
    float denom = 0.f, acc = 0.f;
    for (int j = 0; j < ne; ++j) {
        int s2 = slot2[elist[j]];
        float e = as1[s2 * 8 + h] + adst;
        e = (e >= 0.f) ? e : 0.2f * e;
        float p = expf(e - m);
        denom += p;
        acc = fmaf(p, xw1[(size_t)s2 * 256 + t], acc);
    }
    float out = (ne > 0) ? acc / (denom + 1e-16f) : 0.f;
    out += b1[t];
    // exact GELU: x * 0.5 * (1 + erf(x/sqrt(2)))
    float g = 0.5f * out * (1.f + erff(out * 0.70710678118654752440f));
    h1g[(size_t)k * 256 + t] = g;
}

// ---- xw2 = h1g[k] @ W2^T for layer-1 destination nodes; a_src2/a_dst2 ----
__global__ void k_xw2(const float* __restrict__ h1g, const float* __restrict__ W,
                      const float* __restrict__ attS, const float* __restrict__ attD,
                      const int* cnt, float* xw2, float* as2, float* ad2) {
    int b = blockIdx.x;
    int K1 = min(cnt[1], K1MAX);
    if (b >= K1) return;
    int t = threadIdx.x;
    __shared__ float xs[256];
    __shared__ float redS[256], redD[256];
    xs[t] = h1g[(size_t)b * 256 + t];
    __syncthreads();
    const float* wrow = W + (size_t)t * 256;
    float acc = 0.f;
#pragma unroll 8
    for (int c = 0; c < 256; ++c) acc = fmaf(xs[c], wrow[c], acc);
    xw2[(size_t)b * 256 + t] = acc;
    redS[t] = acc * attS[t];
    redD[t] = acc * attD[t];
    __syncthreads();
    if ((t & 31) == 0) {
        int h = t >> 5;
        float s = 0.f, d = 0.f;
        for (int i = 0; i < 32; ++i) { s += redS[t + i]; d += redD[t + i]; }
        as2[b * 8 + h] = s;
        ad2[b * 8 + h] = d;
    }
}

// ---- final: layer-2 attention for node N-1 only ----
__global__ void k_final(const int* cnt, const int* __restrict__ slot1,
                        const int* __restrict__ e2src,
                        const float* __restrict__ xw2, const float* __restrict__ as2,
                        const float* __restrict__ ad2,
                        const float* __restrict__ b2, float* __restrict__ out) {
    int t = threadIdx.x;
    int h = t >> 5;
    int c2 = min(cnt[0], C2MAX);
    int kd = slot1[N_NODES - 1];
    __shared__ int eslot[C2MAX];
    for (int j = t; j < c2; j += 256) eslot[j] = slot1[e2src[j]];
    __syncthreads();
    float adst = ad2[kd * 8 + h];
    float m = -INFINITY;
    for (int j = 0; j < c2; ++j) {
        float e = as2[eslot[j] * 8 + h] + adst;
        e = (e >= 0.f) ? e : 0.2f * e;
        m = fmaxf(m, e);
    }
    float denom = 0.f, acc = 0.f;
    for (int j = 0; j < c2; ++j) {
        int kk = eslot[j];
        float e = as2[kk * 8 + h] + adst;
        e = (e >= 0.f) ? e : 0.2f * e;
        float p = expf(e - m);
        denom += p;
        acc = fmaf(p, xw2[(size_t)kk * 256 + t], acc);
    }
    float o = (c2 > 0) ? acc / (denom + 1e-16f) : 0.f;
    out[t] = o + b2[t];
}

extern "C" void kernel_launch(void* const* d_in, const int* in_sizes, int n_in,
                              void* d_out, int out_size, void* d_ws, size_t ws_size,
                              hipStream_t stream) {
    const float* x    = (const float*)d_in[0];
    const int*   eidx = (const int*)d_in[1];
    const int*   esrc = eidx;
    const int*   edst = eidx + N_EDGES;
    const float* W1   = (const float*)d_in[2];
    const float* aS1  = (const float*)d_in[3];
    const float* aD1  = (const float*)d_in[4];
    const float* b1   = (const float*)d_in[5];
    const float* W2   = (const float*)d_in[6];
    const float* aS2  = (const float*)d_in[7];
    const float* aD2  = (const float*)d_in[8];
    const float* b2   = (const float*)d_in[9];
    float* out = (float*)d_out;

    // ---- workspace carve (≈3.8 MB) ----
    char* p = (char*)d_ws;
    int* cnt    = (int*)p; p += 256;                       // [0]=c2 [1]=K1 [2]=c1 [3]=n2
    int* slot1  = (int*)p; p += N_NODES * sizeof(int);     // node -> layer1-dst slot
    int* slot2  = (int*)p; p += N_NODES * sizeof(int);     // node -> xw1 slot (contiguous w/ slot1)
    int* e2src  = (int*)p; p += C2MAX * sizeof(int);
    int* l1k    = (int*)p; p += E1MAX * sizeof(int);
    int* l1src  = (int*)p; p += E1MAX * sizeof(int);
    int* nodes1 = (int*)p; p += K1MAX * sizeof(int);
    int* nodes2 = (int*)p; p += N2MAX * sizeof(int);
    float* xw1  = (float*)p; p += (size_t)N2MAX * 256 * sizeof(float);
    float* as1  = (float*)p; p += (size_t)N2MAX * 8 * sizeof(float);
    float* ad1  = (float*)p; p += (size_t)N2MAX * 8 * sizeof(float);
    float* h1g  = (float*)p; p += (size_t)K1MAX * 256 * sizeof(float);
    float* xw2  = (float*)p; p += (size_t)K1MAX * 256 * sizeof(float);
    float* as2  = (float*)p; p += (size_t)K1MAX * 8 * sizeof(float);
    float* ad2  = (float*)p; p += (size_t)K1MAX * 8 * sizeof(float);

    hipMemsetAsync(cnt, 0, 256, stream);
    hipMemsetAsync(slot1, 0xFF, 2 * N_NODES * sizeof(int), stream);  // slot1+slot2 -> -1

    const int EB = (N_EDGES + 255) / 256;
    const int NB = (N_NODES + 255) / 256;

    k_find2  <<<EB, 256, 0, stream>>>(esrc, edst, cnt, slot1, e2src);
    k_compact1<<<NB, 256, 0, stream>>>(cnt, slot1, nodes1);
    k_find1  <<<EB, 256, 0, stream>>>(esrc, edst, cnt, slot1, nodes1, l1k, l1src, slot2);
    k_compact2<<<NB, 256, 0, stream>>>(cnt, slot2, nodes2);
    k_xw1    <<<N2MAX, 256, 0, stream>>>(x, W1, aS1, aD1, cnt, nodes2, xw1, as1, ad1);
    k_attn1  <<<K1MAX, 256, 0, stream>>>(cnt, nodes1, slot2, l1k, l1src, xw1, as1, ad1, b1, h1g);
    k_xw2    <<<K1MAX, 256, 0, stream>>>(h1g, W2, aS2, aD2, cnt, xw2, as2, ad2);
    k_final  <<<1, 256, 0, stream>>>(cnt, slot1, e2src, xw2, as2, ad2, b2, out);
}